// Round 4
// baseline (144.822 us; speedup 1.0000x reference)
//
#include <hip/hip_runtime.h>

typedef _Float16 half8 __attribute__((ext_vector_type(8)));
typedef float floatx4 __attribute__((ext_vector_type(4)));

constexpr int C = 32, H = 512, W = 512, HW = H * W;
constexpr int TBW = 32;            // output px per block (column width)
constexpr int TLH = 8;             // output rows per tile
constexpr int NT  = 2;             // tiles marched per block -> 16 output rows
constexpr int PX  = TBW + 8;       // 40 staged px per row (w0-4 .. w0+35)
constexpr int PXW = 20;            // words/px: 16 x-fp16 + 2 depth(e-,e+) + 2 pad
constexpr int ROWW = PX * PXW + 4; // 804; %32==4 skews row base banks
constexpr int NSLOT = 18;          // input rows gr=-1..16 -> slots 0..17 (no wrap)

__device__ __forceinline__ unsigned pack2h(float lo, float hi) {
    unsigned a = (unsigned)__builtin_bit_cast(unsigned short, (_Float16)lo);
    unsigned b = (unsigned)__builtin_bit_cast(unsigned short, (_Float16)hi);
    return a | (b << 16);
}

// ---- tiny kernel: weights -> per-lane fp16 A-fragment uint4s (18.4 KB, L2-hot)
__global__ __launch_bounds__(256) void pack_w(const float* __restrict__ weight,
                                              uint4* __restrict__ wp) {
    int j = blockIdx.x * 256 + threadIdx.x;
    if (j >= 1152) return;                       // 9 taps * 2 halves * 64 lanes
    int lane = j & 63, half = (j >> 6) & 1, tap = j >> 7;
    int o = half * 16 + (lane & 15), q = lane >> 4;
    uint4 v;
    v.x = pack2h(weight[(o * 32 + q * 8 + 0) * 9 + tap], weight[(o * 32 + q * 8 + 1) * 9 + tap]);
    v.y = pack2h(weight[(o * 32 + q * 8 + 2) * 9 + tap], weight[(o * 32 + q * 8 + 3) * 9 + tap]);
    v.z = pack2h(weight[(o * 32 + q * 8 + 4) * 9 + tap], weight[(o * 32 + q * 8 + 5) * 9 + tap]);
    v.w = pack2h(weight[(o * 32 + q * 8 + 6) * 9 + tap], weight[(o * 32 + q * 8 + 7) * 9 + tap]);
    wp[j] = v;
}

// ---- fused marching conv: block = 32-px column x 16 rows (2 tiles of 8).
// LDS = 18-row window, slots 0..17 = input rows h0-1 .. h0+16 (linear, no ring).
// Pipeline: stage T0 | issue T1 loads | bar | compute T0 | write T1 | bar | compute T1.
// T1's global-load latency hides under T0's compute (T14 issue-early/write-late).
__global__ __launch_bounds__(256, 2) void depthconv_fused(
    const float* __restrict__ x, const float* __restrict__ depth,
    const uint4* __restrict__ wp, const float* __restrict__ bias,
    float* __restrict__ out)
{
    __shared__ __attribute__((aligned(16))) unsigned xsl[NSLOT * ROWW];  // 57.9 KB

    // XCD-contiguous mapping: xcd = bid&7 owns one 64-px stripe (wseg pair).
    const int bid  = blockIdx.x;
    const int xcd  = bid & 7, sub = (bid >> 3) & 1;
    const int hseg = (bid >> 4) & 31, b = bid >> 9;
    const int wseg = xcd * 2 + sub;
    const int h0 = hseg * (TLH * NT), w0 = wseg * TBW;
    const int tid = threadIdx.x;

    const int lane = tid & 63, wid = tid >> 6;
    const int nn = lane & 15, q = lane >> 4;
    const int chh = wid >> 1;                    // output-channel half
    const int pcl = (wid & 1) * 16 + nn;         // tile-local output px 0..31

    // A-frags + bias first: global latency overlaps stage-0 loads
    half8 af[9];
    #pragma unroll
    for (int tap = 0; tap < 9; ++tap)
        af[tap] = __builtin_bit_cast(half8, wp[(tap * 2 + chh) * 64 + lane]);
    float bv[4];
    #pragma unroll
    for (int i = 0; i < 4; ++i) bv[i] = bias[chh * 16 + q * 4 + i];

    // ---- stage tile0: x rows gr=-1..8 -> slots 0..9 (load+pack+write)
    #pragma unroll
    for (int k = 0; k < 7; ++k) {
        int u = tid + k * 256;
        if (u < 1600) {                          // 10 r * 16 cp * 10 f4
            int f4 = u % 10, t = u / 10, r = t % 10, cp = t / 10;
            int h = h0 - 1 + r, wst = w0 - 4 + f4 * 4;
            bool valid = ((unsigned)h < (unsigned)H) && ((unsigned)wst < (unsigned)W);
            float4 va = {0.f, 0.f, 0.f, 0.f}, vb = {0.f, 0.f, 0.f, 0.f};
            if (valid) {
                const float* xb = x + ((size_t)(b * C + 2 * cp)) * HW + (size_t)h * W + wst;
                va = *(const float4*)xb;
                vb = *(const float4*)(xb + HW);
            }
            unsigned* dst = &xsl[r * ROWW + (f4 * 4) * PXW + cp];
            dst[0 * PXW] = pack2h(va.x, vb.x);
            dst[1 * PXW] = pack2h(va.y, vb.y);
            dst[2 * PXW] = pack2h(va.z, vb.z);
            dst[3 * PXW] = pack2h(va.w, vb.w);
        }
    }

    // ---- ISSUE tile1 x loads (rows gr=9..16) into registers; write after compute T0
    float4 hva[5], hvb[5];
    #pragma unroll
    for (int uu = 0; uu < 5; ++uu) {
        int u = tid + uu * 256;                  // 8 r * 16 cp * 10 f4 = 1280, exact
        int f4 = u % 10, t = u / 10, r = t & 7, cp = t >> 3;
        int h = h0 + 9 + r, wst = w0 - 4 + f4 * 4;
        bool valid = ((unsigned)h < (unsigned)H) && ((unsigned)wst < (unsigned)W);
        float4 z = {0.f, 0.f, 0.f, 0.f};
        const float* xb = x + ((size_t)(b * C + 2 * cp)) * HW + (size_t)h * W + wst;
        hva[uu] = valid ? *(const float4*)xb : z;
        hvb[uu] = valid ? *(const float4*)(xb + HW) : z;
    }

    // ---- stage tile0 depth: rows gr=-1..8 -> slot words 16..17 (+exp VALU covers L1)
    #pragma unroll
    for (int k = 0; k < 2; ++k) {
        int u = tid + k * 256;
        if (u < 400) {
            int px = u % PX, r = u / PX;
            int h = h0 - 1 + r, ww = w0 - 4 + px;
            bool valid = ((unsigned)h < (unsigned)H) && ((unsigned)ww < (unsigned)W);
            float d = valid ? depth[(size_t)b * HW + (size_t)h * W + ww] : 0.f;
            float2 e = valid ? make_float2(__expf(-8.3f * d), __expf(8.3f * d))
                             : make_float2(0.f, 0.f);
            *(float2*)&xsl[r * ROWW + px * PXW + 16] = e;
        }
    }

    // ---- issue tile1 depth loads (rows gr=9..16), held raw
    float hd0 = 0.f, hd1 = 0.f;
    {
        int px = tid % PX, r = tid / PX;         // u = tid: r 0..6
        int h = h0 + 9 + r, ww = w0 - 4 + px;
        if (((unsigned)h < (unsigned)H) && ((unsigned)ww < (unsigned)W))
            hd0 = depth[(size_t)b * HW + (size_t)h * W + ww];
    }
    if (tid < 64) {
        int u = tid + 256; int px = u % PX, r = u / PX;   // r 6,7
        int h = h0 + 9 + r, ww = w0 - 4 + px;
        if (((unsigned)h < (unsigned)H) && ((unsigned)ww < (unsigned)W))
            hd1 = depth[(size_t)b * HW + (size_t)h * W + ww];
    }

    __syncthreads();

    #pragma unroll
    for (int kt = 0; kt < NT; ++kt) {
        // ---- compute tile kt (reads slots kt*8 .. kt*8+9)
        floatx4 acc[TLH];
        #pragma unroll
        for (int i = 0; i < 4; ++i) {
            float bvv = bv[i];
            #pragma unroll
            for (int o = 0; o < TLH; ++o) acc[o][i] = bvv;
        }

        float2 dc[TLH];                          // center (em,ep) per output row
        #pragma unroll
        for (int o = 0; o < TLH; ++o)
            dc[o] = *(const float2*)&xsl[(kt * 8 + o + 1) * ROWW + (pcl + 4) * PXW + 16];

        #pragma unroll
        for (int r = 0; r < 10; ++r) {
            const int slot = kt * 8 + r;
            uint4 xraw[3]; float2 dn[3];
            #pragma unroll
            for (int kj = 0; kj < 3; ++kj) {
                int p = pcl + 3 + kj;
                xraw[kj] = *(const uint4*)&xsl[slot * ROWW + p * PXW + 4 * q];
                dn[kj]   = *(const float2*)&xsl[slot * ROWW + p * PXW + 16];
            }
            #pragma unroll
            for (int kj = 0; kj < 3; ++kj) {
                #pragma unroll
                for (int ki = 0; ki < 3; ++ki) {
                    int o = r - ki;
                    if (o < 0 || o >= TLH) continue;   // compile-time
                    int tap = ki * 3 + kj;
                    float s = fminf(dn[kj].y * dc[o].x, dn[kj].x * dc[o].y);
                    _Float16 hs = (_Float16)s;
                    half8 sv = { hs, hs, hs, hs, hs, hs, hs, hs };
                    half8 bf = __builtin_bit_cast(half8, xraw[kj]) * sv;
                    acc[o] = __builtin_amdgcn_mfma_f32_16x16x32_f16(af[tap], bf, acc[o], 0, 0, 0);
                }
            }
        }

        // ---- epilogue tile kt (also buys time for tile1 loads in flight)
        const int pw = w0 + pcl;
        #pragma unroll
        for (int o = 0; o < TLH; ++o) {
            float* op = out + (size_t)b * C * HW + (size_t)(h0 + kt * 8 + o) * W + pw;
            #pragma unroll
            for (int i = 0; i < 4; ++i)
                op[(size_t)(chh * 16 + q * 4 + i) * HW] = acc[o][i];
        }

        if (kt + 1 < NT) {
            // ---- write tile1 (slots 10..17; disjoint from tile0's read set 0..9)
            #pragma unroll
            for (int uu = 0; uu < 5; ++uu) {
                int u = tid + uu * 256;
                int f4 = u % 10, t = u / 10, r = t & 7, cp = t >> 3;
                unsigned* dst = &xsl[(10 + r) * ROWW + (f4 * 4) * PXW + cp];
                float4 va = hva[uu], vb = hvb[uu];
                dst[0 * PXW] = pack2h(va.x, vb.x);
                dst[1 * PXW] = pack2h(va.y, vb.y);
                dst[2 * PXW] = pack2h(va.z, vb.z);
                dst[3 * PXW] = pack2h(va.w, vb.w);
            }
            {
                int px = tid % PX, r = tid / PX;
                int h = h0 + 9 + r, ww = w0 - 4 + px;
                bool valid = ((unsigned)h < (unsigned)H) && ((unsigned)ww < (unsigned)W);
                float2 e = valid ? make_float2(__expf(-8.3f * hd0), __expf(8.3f * hd0))
                                 : make_float2(0.f, 0.f);
                *(float2*)&xsl[(10 + r) * ROWW + px * PXW + 16] = e;
            }
            if (tid < 64) {
                int u = tid + 256; int px = u % PX, r = u / PX;
                int h = h0 + 9 + r, ww = w0 - 4 + px;
                bool valid = ((unsigned)h < (unsigned)H) && ((unsigned)ww < (unsigned)W);
                float2 e = valid ? make_float2(__expf(-8.3f * hd1), __expf(8.3f * hd1))
                                 : make_float2(0.f, 0.f);
                *(float2*)&xsl[(10 + r) * ROWW + px * PXW + 16] = e;
            }
            __syncthreads();
        }
    }
}

extern "C" void kernel_launch(void* const* d_in, const int* in_sizes, int n_in,
                              void* d_out, int out_size, void* d_ws, size_t ws_size,
                              hipStream_t stream) {
    const float* x      = (const float*)d_in[0];
    const float* depth  = (const float*)d_in[1];
    const float* weight = (const float*)d_in[2];
    const float* bias   = (const float*)d_in[3];
    float* out          = (float*)d_out;

    uint4* wpk = (uint4*)d_ws;                   // 18.4 KB, only ws user

    hipLaunchKernelGGL(pack_w, dim3(5), dim3(256), 0, stream, weight, wpk);
    // grid: 2 b * 32 hseg(16 rows) * 2 sub * 8 xcd = 1024
    hipLaunchKernelGGL(depthconv_fused, dim3(1024), dim3(256), 0, stream,
                       x, depth, wpk, bias, out);
}